// Round 3
// baseline (140.121 us; speedup 1.0000x reference)
//
#include <hip/hip_runtime.h>

#define MNODES 384
#define RTHRESH 0.05f
#define NBLK 1536    // one block per node; 6 blocks/CU -> 12 waves/CU
#define NTHR 128     // 2 waves per node

// ---------------------------------------------------------------------------
// 4 plain launches (kernel boundaries carry the cross-block phi dependency;
// cooperative fusion regressed 2.5x: device-scope fences invalidate L2).
//   K0: adj + phi(t=0) -> phiA
//   K1: agg0+g0 (x -> stateA) + phi(t=1) -> phiB
//   K2: agg1+g1 (stateA -> stateB) + phi(t=2) -> phiA
//   K3: agg2+g2 (stateB -> out)
// Decomposition: block = 1 node, 2 waves. Wave w owns phi columns
// [64w, 64w+64) (1 neuron per lane, sequential c-order per neuron -> exact).
// The small g-MLP is DUPLICATED on both waves (identical order -> identical
// bits) so no barrier is needed to share its result. Neighbor lists are
// 2 ballot-compacted sections (one per wave); agg-max is order-independent.
// Workspace layout (bytes):
//   lists @ 0        : 1536*(192+192) u16 (1179648)   section w at +192*w
//   cnt2  @ 1179648  : 1536*2 u16          (6144)
//   phiA  @ 1185792  : 1536*128 f32        (786432)
//   phiB  @ 1972224  : 1536*128 f32        (786432)
//   stateA@ 2758656  : 1536*3 f32          (18432)
//   stateB@ 2777088  : 1536*3 f32          (18432)
// ---------------------------------------------------------------------------

// K0: adjacency (per-wave ballot-compacted sections) + phi(t=0).
__global__ __launch_bounds__(NTHR) void adj_phi0_kernel(
    const float* __restrict__ x,
    const float* __restrict__ fW1, const float* __restrict__ fb1,
    const float* __restrict__ fW2, const float* __restrict__ fb2,
    const float* __restrict__ fW3, const float* __restrict__ fb3,
    unsigned short* __restrict__ cnt2, unsigned short* __restrict__ lists,
    float* __restrict__ phiA)
{
    __shared__ float xs[MNODES * 3];
    __shared__ float H1L[2][64];
    __shared__ float H2[128];
    const int tid = threadIdx.x;
    const int wv = tid >> 6, lane = tid & 63;
    const int node = blockIdx.x;            // [0,1536)
    const int n = node / MNODES;
    const int i = node - n * MNODES;

    for (int idx = tid; idx < MNODES * 3; idx += NTHR)
        xs[idx] = x[n * MNODES * 3 + idx];
    __syncthreads();

    const float s0 = xs[i * 3], s1 = xs[i * 3 + 1], s2 = xs[i * 3 + 2];

    // adjacency: wave w covers j in [192w, 192w+192), compacted into its own
    // section (list order is irrelevant: agg is an exact max).
    unsigned short* ml = lists + (size_t)node * MNODES + wv * 192;
    int nc = 0;
#pragma unroll
    for (int rep = 0; rep < 3; ++rep) {
        const int j = wv * 192 + rep * 64 + lane;
        float dx = xs[j * 3] - s0;
        float dy = xs[j * 3 + 1] - s1;
        float dz = xs[j * 3 + 2] - s2;
        // match numpy rounding exactly (no fp-contract): (dx*dx + dy*dy) + dz*dz
        float d2 = __fadd_rn(__fadd_rn(__fmul_rn(dx, dx), __fmul_rn(dy, dy)),
                             __fmul_rn(dz, dz));
        const bool a = d2 < RTHRESH;
        const unsigned long long m = __ballot(a);
        if (a) ml[nc + __popcll(m & ((1ull << lane) - 1ull))] = (unsigned short)j;
        nc += (int)__popcll(m);
    }
    if (lane == 0) cnt2[node * 2 + wv] = (unsigned short)nc;

    // phi(t=0): L1 duplicated per wave; L2/L3 split (1 neuron per lane).
    // Layer 1 (effective 3->64; rel slot of the edge input is exactly zero,
    // so rows 0..2 of fW1 are provably unused)
    float v = fb1[lane];
    v = fmaf(s0, fW1[3 * 64 + lane], v);
    v = fmaf(s1, fW1[4 * 64 + lane], v);
    v = fmaf(s2, fW1[5 * 64 + lane], v);
    H1L[wv][lane] = fmaxf(v, 0.0f);

    const int col = wv * 64 + lane;
    float a2 = fb2[col];
#pragma unroll 16
    for (int c = 0; c < 64; ++c)
        a2 = fmaf(H1L[wv][c], fW2[c * 128 + col], a2);
    H2[col] = fmaxf(a2, 0.0f);
    __syncthreads();

    float c0 = fb3[col];
#pragma unroll 16
    for (int c = 0; c < 128; ++c)
        c0 = fmaf(H2[c], fW3[c * 128 + col], c0);
    phiA[(size_t)node * 128 + col] = fmaxf(c0, 0.0f);
}

// K1..K3: agg(t)+g(t) (+ phi(t+1) when do_phi). Block per node, 2 waves.
__global__ __launch_bounds__(NTHR) void step_kernel(
    const float* __restrict__ phisrc, float* __restrict__ phidst,
    const unsigned short* __restrict__ cnt2, const unsigned short* __restrict__ lists,
    const float* __restrict__ statesrc, float* __restrict__ statedst,
    const float* __restrict__ gW1, const float* __restrict__ gb1,
    const float* __restrict__ gW2, const float* __restrict__ gb2,
    const float* __restrict__ gW3, const float* __restrict__ gb3,
    const float* __restrict__ fW1n, const float* __restrict__ fb1n,
    const float* __restrict__ fW2n, const float* __restrict__ fb2n,
    const float* __restrict__ fW3n, const float* __restrict__ fb3n,
    int do_phi)
{
    __shared__ float aggL[128];
    __shared__ float H2[128];
    __shared__ float H1L[2][64];
    __shared__ float h1L[2][64];
    __shared__ float h2L[2][32];
    const int tid = threadIdx.x;
    const int wv = tid >> 6, lane = tid & 63;
    const int node = blockIdx.x;
    const int n = node / MNODES;
    const int nbase = n * MNODES;
    const int s0c = cnt2[node * 2 + 0];
    const int s1c = cnt2[node * 2 + 1];
    const int nc = s0c + s1c;               // >= 1 (self-edge: d2 = 0 < R)
    const unsigned short* ml = lists + (size_t)node * MNODES;
    const float* pb = phisrc + (size_t)nbase * 128;
    const int col = wv * 64 + lane;

    // agg: max over neighbors for this wave's column. phi >= 0 and
    // non-neighbors contribute 0 in the reference, so init 0 is exact.
    // 8-wide with index clamping: re-reading the last neighbor is harmless
    // under max. Merged two-section index mapping.
    float m[8];
#pragma unroll
    for (int k = 0; k < 8; ++k) m[k] = 0.0f;
    const int last = nc - 1;
    for (int jj = 0; jj < nc; jj += 8) {
        const float* r[8];
#pragma unroll
        for (int k = 0; k < 8; ++k) {
            int jc = jj + k;
            jc = jc < last ? jc : last;
            const int idx = jc < s0c ? jc : 192 + (jc - s0c);
            r[k] = pb + (size_t)ml[idx] * 128;
        }
#pragma unroll
        for (int k = 0; k < 8; ++k) m[k] = fmaxf(m[k], r[k][col]);
    }
    aggL[col] = fmaxf(fmaxf(fmaxf(m[0], m[1]), fmaxf(m[2], m[3])),
                      fmaxf(fmaxf(m[4], m[5]), fmaxf(m[6], m[7])));
    __syncthreads();

    // g-MLP duplicated on both waves (identical op order -> identical bits;
    // avoids cross-wave result broadcast and keeps both waves busy).
    // g1: 128 -> 64
    float h = gb1[lane];
#pragma unroll 16
    for (int c = 0; c < 128; ++c) h = fmaf(aggL[c], gW1[c * 64 + lane], h);
    h1L[wv][lane] = fmaxf(h, 0.0f);
    // g2: 64 -> 32
    if (lane < 32) {
        float v2 = gb2[lane];
#pragma unroll 16
        for (int k = 0; k < 64; ++k) v2 = fmaf(h1L[wv][k], gW2[k * 32 + lane], v2);
        h2L[wv][lane] = fmaxf(v2, 0.0f);
    }
    // g3: 32 -> 3, final relu, residual
    float ns = 0.0f;
    if (lane < 3) {
        const float sv = statesrc[node * 3 + lane];
        float v3 = gb3[lane];
#pragma unroll
        for (int q = 0; q < 32; ++q) v3 = fmaf(h2L[wv][q], gW3[q * 3 + lane], v3);
        ns = fmaxf(v3, 0.0f) + sv;
        if (wv == 0) statedst[node * 3 + lane] = ns;
    }

    if (do_phi) {
        const float t0 = __shfl(ns, 0), t1 = __shfl(ns, 1), t2 = __shfl(ns, 2);
        // phi(t+1): L1 duplicated per wave; L2/L3 split (1 neuron per lane).
        float v = fb1n[lane];
        v = fmaf(t0, fW1n[3 * 64 + lane], v);
        v = fmaf(t1, fW1n[4 * 64 + lane], v);
        v = fmaf(t2, fW1n[5 * 64 + lane], v);
        H1L[wv][lane] = fmaxf(v, 0.0f);

        float a2 = fb2n[col];
#pragma unroll 16
        for (int c = 0; c < 64; ++c)
            a2 = fmaf(H1L[wv][c], fW2n[c * 128 + col], a2);
        H2[col] = fmaxf(a2, 0.0f);
        __syncthreads();

        float c0 = fb3n[col];
#pragma unroll 16
        for (int c = 0; c < 128; ++c)
            c0 = fmaf(H2[c], fW3n[c * 128 + col], c0);
        phidst[(size_t)node * 128 + col] = fmaxf(c0, 0.0f);
    }
}

extern "C" void kernel_launch(void* const* d_in, const int* in_sizes, int n_in,
                              void* d_out, int out_size, void* d_ws, size_t ws_size,
                              hipStream_t stream) {
    const float* x   = (const float*)d_in[0];
    // d_in[1..6] = hW1..hb3 : provably unused (delta MLP receives exact zeros)
    const float* fW1 = (const float*)d_in[7];
    const float* fb1 = (const float*)d_in[8];
    const float* fW2 = (const float*)d_in[9];
    const float* fb2 = (const float*)d_in[10];
    const float* fW3 = (const float*)d_in[11];
    const float* fb3 = (const float*)d_in[12];
    const float* gW1 = (const float*)d_in[13];
    const float* gb1 = (const float*)d_in[14];
    const float* gW2 = (const float*)d_in[15];
    const float* gb2 = (const float*)d_in[16];
    const float* gW3 = (const float*)d_in[17];
    const float* gb3 = (const float*)d_in[18];

    char* ws = (char*)d_ws;
    unsigned short* lists = (unsigned short*)(ws + 0);
    unsigned short* cnt2  = (unsigned short*)(ws + 1179648);
    float* phiA           = (float*)(ws + 1185792);
    float* phiB           = (float*)(ws + 1972224);
    float* stateA         = (float*)(ws + 2758656);
    float* stateB         = (float*)(ws + 2777088);
    float* outp           = (float*)d_out;

    // K0: adj + phi0 -> phiA
    adj_phi0_kernel<<<NBLK, NTHR, 0, stream>>>(
        x, fW1, fb1, fW2, fb2, fW3, fb3, cnt2, lists, phiA);
    // K1: agg0+g0 (x -> stateA) + phi1 -> phiB
    step_kernel<<<NBLK, NTHR, 0, stream>>>(
        phiA, phiB, cnt2, lists, x, stateA,
        gW1, gb1, gW2, gb2, gW3, gb3,
        fW1 + 384, fb1 + 64, fW2 + 8192, fb2 + 128,
        fW3 + 16384, fb3 + 128, 1);
    // K2: agg1+g1 (stateA -> stateB) + phi2 -> phiA
    step_kernel<<<NBLK, NTHR, 0, stream>>>(
        phiB, phiA, cnt2, lists, stateA, stateB,
        gW1 + 8192, gb1 + 64, gW2 + 2048, gb2 + 32,
        gW3 + 96, gb3 + 3,
        fW1 + 768, fb1 + 128, fW2 + 16384, fb2 + 256,
        fW3 + 32768, fb3 + 256, 1);
    // K3: agg2+g2 (stateB -> out)
    step_kernel<<<NBLK, NTHR, 0, stream>>>(
        phiA, phiB, cnt2, lists, stateB, outp,
        gW1 + 16384, gb1 + 128, gW2 + 4096, gb2 + 64,
        gW3 + 192, gb3 + 6,
        fW1, fb1, fW2, fb2, fW3, fb3, 0);
}

// Round 4
// 136.614 us; speedup vs baseline: 1.0257x; 1.0257x over previous
//
#include <hip/hip_runtime.h>

#define MNODES 384
#define RTHRESH 0.05f

// ---------------------------------------------------------------------------
// 4 plain launches (kernel boundaries carry the cross-block phi dependency).
// Fusion experiments (round 1/3 of this session): cooperative grid.sync
// regressed 2.5x (device-scope fences invalidate per-XCD L2 -> weights
// re-stream); occupancy doubling was exactly neutral -> wall time is
// dominated by a fixed ~115us harness component, bodies are small.
// This round: exact revert to the harness-verified 133.8us structure
// (384 blocks x 256 thr, wave-per-node, (lane,lane+64) neuron split)
// + fW3 staged in LDS for the step kernels (shared by 4 waves, issued
// before agg so the global loads overlap agg/g compute).
//   K0: adj + phi(t=0) -> phiA
//   K1: agg0+g0 (-> stateA) + phi(t=1) -> phiB
//   K2: agg1+g1 (stateA -> stateB) + phi(t=2) -> phiA
//   K3: agg2+g2 -> d_out
// Workspace layout (bytes):
//   lists  @ 0        : 1536*384 u16  (1179648)
//   cnt    @ 1179648  : 1536 int      (6144)
//   phiA   @ 1185792  : 1536*128 f32  (786432)
//   phiB   @ 1972224  : 1536*128 f32  (786432)
//   stateA @ 2758656  : 1536*3 f32    (18432)
//   stateB @ 2777088  : 1536*3 f32    (18432)
// ---------------------------------------------------------------------------

// phi[node][128] = relu(W3^T relu(W2^T relu(W1[3:6]^T s + b1) + b2) + b3)
// One wave per node; lane computes neurons lane and lane+64. H1/H2 are
// per-wave LDS: wave-internal DS ordering makes barriers unnecessary
// (validated bit-exact in a prior round). Used by K0 (global fW3).
__device__ __forceinline__ void phi_stage(
    const float* __restrict__ fW1, const float* __restrict__ fb1,
    const float* __restrict__ fW2, const float* __restrict__ fb2,
    const float* __restrict__ fW3, const float* __restrict__ fb3,
    float s0, float s1, float s2, int lane,
    float* __restrict__ H1, float* __restrict__ H2,
    float* __restrict__ phidst /* this node's 128-float row */)
{
    // Layer 1 (effective 3->64; rel slot of the edge input is exactly zero,
    // so rows 0..2 of fW1 are provably unused)
    float v = fb1[lane];
    v = fmaf(s0, fW1[3 * 64 + lane], v);
    v = fmaf(s1, fW1[4 * 64 + lane], v);
    v = fmaf(s2, fW1[5 * 64 + lane], v);
    H1[lane] = fmaxf(v, 0.0f);
    // Layer 2: 64 -> 128
    float a0 = fb2[lane], a1 = fb2[lane + 64];
#pragma unroll 16
    for (int c = 0; c < 64; ++c) {
        const float h = H1[c];
        a0 = fmaf(h, fW2[c * 128 + lane], a0);
        a1 = fmaf(h, fW2[c * 128 + lane + 64], a1);
    }
    H2[lane] = fmaxf(a0, 0.0f);
    H2[lane + 64] = fmaxf(a1, 0.0f);
    // Layer 3: 128 -> 128, final relu
    float c0 = fb3[lane], c1 = fb3[lane + 64];
#pragma unroll 16
    for (int c = 0; c < 128; ++c) {
        const float h = H2[c];
        c0 = fmaf(h, fW3[c * 128 + lane], c0);
        c1 = fmaf(h, fW3[c * 128 + lane + 64], c1);
    }
    phidst[lane] = fmaxf(c0, 0.0f);
    phidst[lane + 64] = fmaxf(c1, 0.0f);
}

// K0: adjacency (ballot-compacted neighbor lists) + phi(t=0).
__global__ __launch_bounds__(256) void adj_phi0_kernel(
    const float* __restrict__ x,
    const float* __restrict__ fW1, const float* __restrict__ fb1,
    const float* __restrict__ fW2, const float* __restrict__ fb2,
    const float* __restrict__ fW3, const float* __restrict__ fb3,
    int* __restrict__ cnt, unsigned short* __restrict__ lists,
    float* __restrict__ phiA)
{
    __shared__ float xs[MNODES * 3];
    __shared__ float work[4][192];
    const int tid = threadIdx.x;
    const int wv = tid >> 6, lane = tid & 63;
    const int node = blockIdx.x * 4 + wv;      // [0,1536)
    const int n = blockIdx.x / 96;             // batch
    const int i = node - n * MNODES;

    for (int idx = tid; idx < MNODES * 3; idx += 256)
        xs[idx] = x[n * MNODES * 3 + idx];
    __syncthreads();

    const float s0 = xs[i * 3], s1 = xs[i * 3 + 1], s2 = xs[i * 3 + 2];
    unsigned short* ml = lists + (size_t)node * MNODES;
    int nc = 0;
#pragma unroll
    for (int rep = 0; rep < 6; ++rep) {
        const int j = rep * 64 + lane;
        float dx = xs[j * 3] - s0;
        float dy = xs[j * 3 + 1] - s1;
        float dz = xs[j * 3 + 2] - s2;
        // match numpy rounding exactly (no fp-contract): (dx*dx + dy*dy) + dz*dz
        float d2 = __fadd_rn(__fadd_rn(__fmul_rn(dx, dx), __fmul_rn(dy, dy)),
                             __fmul_rn(dz, dz));
        const bool a = d2 < RTHRESH;
        const unsigned long long m = __ballot(a);
        if (a) ml[nc + __popcll(m & ((1ull << lane) - 1ull))] = (unsigned short)j;
        nc += (int)__popcll(m);
    }
    if (lane == 0) cnt[node] = nc;

    phi_stage(fW1, fb1, fW2, fb2, fW3, fb3, s0, s1, s2, lane,
              &work[wv][0], &work[wv][64], phiA + (size_t)node * 128);
}

// K1..K3: agg(t)+g(t) (+ phi(t+1) when do_phi). Wave per node.
// fW3 of the NEXT phi is staged into LDS at kernel top (all 256 threads,
// dwordx4), overlapping the agg/g phase; one uniform barrier before use.
__global__ __launch_bounds__(256) void step_kernel(
    const float* __restrict__ phisrc, float* __restrict__ phidst,
    const int* __restrict__ cnt, const unsigned short* __restrict__ lists,
    const float* __restrict__ statesrc, float* __restrict__ statedst,
    const float* __restrict__ gW1, const float* __restrict__ gb1,
    const float* __restrict__ gW2, const float* __restrict__ gb2,
    const float* __restrict__ gW3, const float* __restrict__ gb3,
    const float* __restrict__ fW1n, const float* __restrict__ fb1n,
    const float* __restrict__ fW2n, const float* __restrict__ fb2n,
    const float* __restrict__ fW3n, const float* __restrict__ fb3n,
    int do_phi)
{
    __shared__ float work[4][224];  // aggL[128] | h1[64] | h2[32]; phi reuses [0..192)
    __shared__ float sW3[128 * 128];
    const int tid = threadIdx.x;
    const int wv = tid >> 6, lane = tid & 63;
    const int node = __builtin_amdgcn_readfirstlane(blockIdx.x * 4 + wv);
    const int nbase = (blockIdx.x / 96) * MNODES;

    // stage fW3n -> LDS (value-identical; loads overlap the agg/g phase)
    if (do_phi) {
        const float4* src = (const float4*)fW3n;
        float4* dst = (float4*)sW3;
#pragma unroll 8
        for (int k = 0; k < 16; ++k)
            dst[tid + k * 256] = src[tid + k * 256];
    }

    const int nc = cnt[node];
    const unsigned short* ml = lists + (size_t)node * MNODES;
    const float* pb = phisrc + (size_t)nbase * 128;
    float* const aggL = &work[wv][0];
    float* const h1L  = &work[wv][128];
    float* const h2L  = &work[wv][192];

    // agg: max over neighbors. phi >= 0 and non-neighbors contribute 0 in the
    // reference, so init 0 is exact. 8-wide with index clamping: reading the
    // last neighbor multiple times is harmless under max (no serial cleanup;
    // 16 outstanding 256B loads). nc >= 1 always (self-edge: d2 = 0 < R).
    float m[8], p[8];
#pragma unroll
    for (int k = 0; k < 8; ++k) { m[k] = 0.0f; p[k] = 0.0f; }
    const int last = nc - 1;
    for (int jj = 0; jj < nc; jj += 8) {
        const float* r[8];
#pragma unroll
        for (int k = 0; k < 8; ++k) {
            const int jc = jj + k;
            const int j = ml[jc < last ? jc : last];
            r[k] = pb + (size_t)j * 128;
        }
#pragma unroll
        for (int k = 0; k < 8; ++k) {
            m[k] = fmaxf(m[k], r[k][lane]);
            p[k] = fmaxf(p[k], r[k][lane + 64]);
        }
    }
    aggL[lane] = fmaxf(fmaxf(fmaxf(m[0], m[1]), fmaxf(m[2], m[3])),
                       fmaxf(fmaxf(m[4], m[5]), fmaxf(m[6], m[7])));
    aggL[lane + 64] = fmaxf(fmaxf(fmaxf(p[0], p[1]), fmaxf(p[2], p[3])),
                            fmaxf(fmaxf(p[4], p[5]), fmaxf(p[6], p[7])));

    // g1: 128 -> 64
    float h = gb1[lane];
#pragma unroll 16
    for (int c = 0; c < 128; ++c) h = fmaf(aggL[c], gW1[c * 64 + lane], h);
    h1L[lane] = fmaxf(h, 0.0f);
    // g2: 64 -> 32
    if (lane < 32) {
        float v2 = gb2[lane];
#pragma unroll 16
        for (int k = 0; k < 64; ++k) v2 = fmaf(h1L[k], gW2[k * 32 + lane], v2);
        h2L[lane] = fmaxf(v2, 0.0f);
    }
    // g3: 32 -> 3, final relu, residual
    float sv = 0.0f;
    if (lane < 3) sv = statesrc[node * 3 + lane];
    float ns = 0.0f;
    if (lane < 3) {
        float v3 = gb3[lane];
#pragma unroll
        for (int q = 0; q < 32; ++q) v3 = fmaf(h2L[q], gW3[q * 3 + lane], v3);
        ns = fmaxf(v3, 0.0f) + sv;
        statedst[node * 3 + lane] = ns;
    }
    if (do_phi) {
        const float s0 = __shfl(ns, 0), s1 = __shfl(ns, 1), s2 = __shfl(ns, 2);
        float* const H1 = &work[wv][0];
        float* const H2 = &work[wv][64];
        // Layer 1 (effective 3->64)
        float v = fb1n[lane];
        v = fmaf(s0, fW1n[3 * 64 + lane], v);
        v = fmaf(s1, fW1n[4 * 64 + lane], v);
        v = fmaf(s2, fW1n[5 * 64 + lane], v);
        H1[lane] = fmaxf(v, 0.0f);
        // Layer 2: 64 -> 128
        float a0 = fb2n[lane], a1 = fb2n[lane + 64];
#pragma unroll 16
        for (int c = 0; c < 64; ++c) {
            const float hh = H1[c];
            a0 = fmaf(hh, fW2n[c * 128 + lane], a0);
            a1 = fmaf(hh, fW2n[c * 128 + lane + 64], a1);
        }
        H2[lane] = fmaxf(a0, 0.0f);
        H2[lane + 64] = fmaxf(a1, 0.0f);
        // ensure staged fW3 is complete (uniform barrier: do_phi is uniform,
        // all 256 threads reach here)
        __syncthreads();
        // Layer 3: 128 -> 128 from LDS, final relu
        float c0 = fb3n[lane], c1 = fb3n[lane + 64];
#pragma unroll 16
        for (int c = 0; c < 128; ++c) {
            const float hh = H2[c];
            c0 = fmaf(hh, sW3[c * 128 + lane], c0);
            c1 = fmaf(hh, sW3[c * 128 + lane + 64], c1);
        }
        phidst[(size_t)node * 128 + lane] = fmaxf(c0, 0.0f);
        phidst[(size_t)node * 128 + lane + 64] = fmaxf(c1, 0.0f);
    }
}

extern "C" void kernel_launch(void* const* d_in, const int* in_sizes, int n_in,
                              void* d_out, int out_size, void* d_ws, size_t ws_size,
                              hipStream_t stream) {
    const float* x   = (const float*)d_in[0];
    // d_in[1..6] = hW1..hb3 : provably unused (delta MLP receives exact zeros)
    const float* fW1 = (const float*)d_in[7];
    const float* fb1 = (const float*)d_in[8];
    const float* fW2 = (const float*)d_in[9];
    const float* fb2 = (const float*)d_in[10];
    const float* fW3 = (const float*)d_in[11];
    const float* fb3 = (const float*)d_in[12];
    const float* gW1 = (const float*)d_in[13];
    const float* gb1 = (const float*)d_in[14];
    const float* gW2 = (const float*)d_in[15];
    const float* gb2 = (const float*)d_in[16];
    const float* gW3 = (const float*)d_in[17];
    const float* gb3 = (const float*)d_in[18];

    char* ws = (char*)d_ws;
    unsigned short* lists = (unsigned short*)(ws + 0);
    int* cnt              = (int*)(ws + 1179648);
    float* phiA           = (float*)(ws + 1185792);
    float* phiB           = (float*)(ws + 1972224);
    float* stateA         = (float*)(ws + 2758656);
    float* stateB         = (float*)(ws + 2777088);
    float* outp           = (float*)d_out;

    // K0: adj + phi0 -> phiA
    adj_phi0_kernel<<<384, 256, 0, stream>>>(x, fW1, fb1, fW2, fb2, fW3, fb3,
                                             cnt, lists, phiA);
    // K1: agg0+g0 (x -> stateA) + phi1 -> phiB
    step_kernel<<<384, 256, 0, stream>>>(phiA, phiB, cnt, lists, x, stateA,
                                         gW1, gb1, gW2, gb2, gW3, gb3,
                                         fW1 + 384, fb1 + 64, fW2 + 8192, fb2 + 128,
                                         fW3 + 16384, fb3 + 128, 1);
    // K2: agg1+g1 (stateA -> stateB) + phi2 -> phiA
    step_kernel<<<384, 256, 0, stream>>>(phiB, phiA, cnt, lists, stateA, stateB,
                                         gW1 + 8192, gb1 + 64, gW2 + 2048, gb2 + 32,
                                         gW3 + 96, gb3 + 3,
                                         fW1 + 768, fb1 + 128, fW2 + 16384, fb2 + 256,
                                         fW3 + 32768, fb3 + 256, 1);
    // K3: agg2+g2 (stateB -> out)
    step_kernel<<<384, 256, 0, stream>>>(phiA, phiB, cnt, lists, stateB, outp,
                                         gW1 + 16384, gb1 + 128, gW2 + 4096, gb2 + 64,
                                         gW3 + 192, gb3 + 6,
                                         fW1, fb1, fW2, fb2, fW3, fb3, 0);
}